// Round 1
// baseline (317.619 us; speedup 1.0000x reference)
//
#include <hip/hip_runtime.h>
#include <stdint.h>

#define B_ 2
#define N_ 2048
#define D_ 1024
#define H_ 16
#define DK 64

typedef __bf16 bf16x8 __attribute__((ext_vector_type(8)));
typedef float f32x4 __attribute__((ext_vector_type(4)));

__device__ __forceinline__ unsigned short f2bf(float f) {
    unsigned int u = __float_as_uint(f);
    u = (u + 0x7FFFu + ((u >> 16) & 1u)) >> 16;
    return (unsigned short)u;
}

// ---------------- convert x (f32 -> bf16) ----------------
__global__ __launch_bounds__(256) void k_convert_x(const float* __restrict__ x,
                                                   unsigned short* __restrict__ xb, int n4) {
    int i = blockIdx.x * blockDim.x + threadIdx.x;
    int stride = gridDim.x * blockDim.x;
    const float4* x4 = (const float4*)x;
    ushort4* o4 = (ushort4*)xb;
    for (; i < n4; i += stride) {
        float4 v = x4[i];
        ushort4 o;
        o.x = f2bf(v.x); o.y = f2bf(v.y); o.z = f2bf(v.z); o.w = f2bf(v.w);
        o4[i] = o;
    }
}

// ---------------- transpose+convert weights: w (K x C) f32 -> wT (C x K) bf16 ----------------
__global__ __launch_bounds__(256) void k_transpose_w(const float* __restrict__ w,
                                                     unsigned short* __restrict__ wT,
                                                     int K, int C) {
    __shared__ float tile[32][33];
    int c0 = blockIdx.x * 32, k0 = blockIdx.y * 32;
    int tx = threadIdx.x, ty = threadIdx.y;  // 32 x 8
    for (int s = 0; s < 4; ++s)
        tile[ty + 8 * s][tx] = w[(size_t)(k0 + ty + 8 * s) * C + c0 + tx];
    __syncthreads();
    for (int s = 0; s < 4; ++s)
        wT[(size_t)(c0 + ty + 8 * s) * K + k0 + tx] = f2bf(tile[tx][ty + 8 * s]);
}

// ---------------- transpose v: [HB][N][64] -> [HB][64][N] (bf16) ----------------
__global__ __launch_bounds__(256) void k_transpose_v(const unsigned short* __restrict__ v,
                                                     unsigned short* __restrict__ vT) {
    __shared__ unsigned short tile[32][33];
    int hb = blockIdx.z;
    int n0 = blockIdx.x * 32, d0 = blockIdx.y * 32;
    int tx = threadIdx.x, ty = threadIdx.y;
    const unsigned short* src = v + (size_t)hb * (N_ * DK);
    unsigned short* dst = vT + (size_t)hb * (N_ * DK);
    for (int s = 0; s < 4; ++s)
        tile[ty + 8 * s][tx] = src[(size_t)(n0 + ty + 8 * s) * DK + d0 + tx];
    __syncthreads();
    for (int s = 0; s < 4; ++s)
        dst[(size_t)(d0 + ty + 8 * s) * N_ + n0 + tx] = tile[tx][ty + 8 * s];
}

// ---------------- GEMM: C(M x Nn) = A(M x K) * BT(Nn x K)^T + bias ----------------
// MODE 0: scatter to q/k/v bf16 arrays [H][B][N][64] (Cout = q base; k at +4Mi, v at +8Mi)
// MODE 1: fp32 store C row-major
template <int MODE>
__global__ __launch_bounds__(256) void k_gemm(const unsigned short* __restrict__ A,
                                              const unsigned short* __restrict__ BT,
                                              const float* __restrict__ bias,
                                              void* __restrict__ Cout,
                                              int M, int Nn, int K) {
    __shared__ __attribute__((aligned(16))) unsigned short Alds[128 * 64];
    __shared__ __attribute__((aligned(16))) unsigned short Blds[128 * 64];
    int t = threadIdx.x;
    int lane = t & 63, w = t >> 6;
    int quad = lane >> 4, c = lane & 15;
    int wm = w >> 1, wn = w & 1;
    int bi = blockIdx.y, bj = blockIdx.x;
    const unsigned short* Abase = A + (size_t)(bi * 128) * K;
    const unsigned short* Bbase = BT + (size_t)(bj * 128) * K;

    f32x4 acc[4][4];
    for (int mf = 0; mf < 4; ++mf)
        for (int nf = 0; nf < 4; ++nf)
            acc[mf][nf] = (f32x4){0.f, 0.f, 0.f, 0.f};

    for (int k0 = 0; k0 < K; k0 += 64) {
        __syncthreads();
        for (int i = 0; i < 4; ++i) {
            int ch = i * 256 + t;  // 0..1023
            int row = ch >> 3, kc = ch & 7;
            *(uint4*)&Alds[row * 64 + kc * 8] =
                *(const uint4*)&Abase[(size_t)row * K + k0 + kc * 8];
            *(uint4*)&Blds[row * 64 + kc * 8] =
                *(const uint4*)&Bbase[(size_t)row * K + k0 + kc * 8];
        }
        __syncthreads();
        for (int ks = 0; ks < 2; ++ks) {
            bf16x8 af[4], bfr[4];
            for (int mf = 0; mf < 4; ++mf)
                af[mf] = *(const bf16x8*)&Alds[(wm * 64 + mf * 16 + c) * 64 + ks * 32 + quad * 8];
            for (int nf = 0; nf < 4; ++nf)
                bfr[nf] = *(const bf16x8*)&Blds[(wn * 64 + nf * 16 + c) * 64 + ks * 32 + quad * 8];
            for (int mf = 0; mf < 4; ++mf)
                for (int nf = 0; nf < 4; ++nf)
                    acc[mf][nf] = __builtin_amdgcn_mfma_f32_16x16x32_bf16(af[mf], bfr[nf],
                                                                          acc[mf][nf], 0, 0, 0);
        }
    }

    for (int mf = 0; mf < 4; ++mf)
        for (int nf = 0; nf < 4; ++nf) {
            int j = bj * 128 + wn * 64 + nf * 16 + c;
            float bv = bias[j];
            for (int r = 0; r < 4; ++r) {
                int i = bi * 128 + wm * 64 + mf * 16 + quad * 4 + r;
                float v = acc[mf][nf][r] + bv;
                if (MODE == 0) {
                    int h = j / 192, r2 = j % 192;
                    int which = r2 >> 6, d = r2 & 63;
                    int b = i >> 11, n = i & 2047;
                    ((unsigned short*)Cout)[(size_t)which * 4194304 +
                                            (((size_t)(h * 2 + b) * 2048 + n) * 64 + d)] = f2bf(v);
                } else {
                    ((float*)Cout)[(size_t)i * Nn + j] = v;
                }
            }
        }
}

// ---------------- attention: context + rowscale ----------------
// grid (qt=16, hb=32), 256 threads. q/k: [HB][N][64] bf16, vT: [HB][64][N] bf16
__global__ __launch_bounds__(256) void k_attn(const unsigned short* __restrict__ Q,
                                              const unsigned short* __restrict__ Kc,
                                              const unsigned short* __restrict__ VT,
                                              unsigned short* __restrict__ ctx,
                                              float* __restrict__ rowscale) {
    // [0,8192): Q stage then K tile; [8192,16384): VT tile; [16384,32768): P (4 waves x 32 x 128)
    __shared__ __attribute__((aligned(16))) unsigned short lds[32768];
    int t = threadIdx.x, lane = t & 63, w = t >> 6;
    int quad = lane >> 4, c = lane & 15;
    int qt = blockIdx.x, hb = blockIdx.y;
    int h = hb >> 1, b = hb & 1;
    const unsigned short* qbase = Q + (size_t)hb * (N_ * DK) + (size_t)qt * 128 * DK;
    const unsigned short* kbase = Kc + (size_t)hb * (N_ * DK);
    const unsigned short* vtbase = VT + (size_t)hb * (DK * N_);

    // stage Q tile (contiguous 16 KB), read fragments to registers
    for (int i = 0; i < 4; ++i) {
        int ch = i * 256 + t;
        *(uint4*)&lds[ch * 8] = *(const uint4*)&qbase[ch * 8];
    }
    __syncthreads();
    bf16x8 qf[2][2];
    for (int mf = 0; mf < 2; ++mf)
        for (int ks = 0; ks < 2; ++ks)
            qf[mf][ks] = *(const bf16x8*)&lds[(w * 32 + mf * 16 + c) * 64 + ks * 32 + quad * 8];
    __syncthreads();

    f32x4 acc_o[2][4];
    for (int mf = 0; mf < 2; ++mf)
        for (int df = 0; df < 4; ++df)
            acc_o[mf][df] = (f32x4){0.f, 0.f, 0.f, 0.f};
    float lsum[2][4] = {{0.f, 0.f, 0.f, 0.f}, {0.f, 0.f, 0.f, 0.f}};
    unsigned short* Pw = &lds[16384 + w * 4096];

    for (int kb = 0; kb < 16; ++kb) {
        for (int i = 0; i < 4; ++i) {
            int ch = i * 256 + t;
            *(uint4*)&lds[ch * 8] = *(const uint4*)&kbase[(size_t)kb * 8192 + ch * 8];
            int row = ch >> 4, cc = ch & 15;
            *(uint4*)&lds[8192 + row * 128 + cc * 8] =
                *(const uint4*)&vtbase[(size_t)row * N_ + kb * 128 + cc * 8];
        }
        __syncthreads();
        // S = Q K^T   (wave: 32 q-rows x 128 keys)
        f32x4 s[2][8];
        for (int mf = 0; mf < 2; ++mf)
            for (int nf = 0; nf < 8; ++nf)
                s[mf][nf] = (f32x4){0.f, 0.f, 0.f, 0.f};
        for (int ks = 0; ks < 2; ++ks)
            for (int nf = 0; nf < 8; ++nf) {
                bf16x8 kf = *(const bf16x8*)&lds[(nf * 16 + c) * 64 + ks * 32 + quad * 8];
                for (int mf = 0; mf < 2; ++mf)
                    s[mf][nf] = __builtin_amdgcn_mfma_f32_16x16x32_bf16(qf[mf][ks], kf,
                                                                        s[mf][nf], 0, 0, 0);
            }
        // P = exp(s/8); accumulate row sums; stash P (bf16) in LDS
        for (int mf = 0; mf < 2; ++mf)
            for (int nf = 0; nf < 8; ++nf)
                for (int r = 0; r < 4; ++r) {
                    float p = __expf(s[mf][nf][r] * 0.125f);
                    lsum[mf][r] += p;
                    Pw[(mf * 16 + quad * 4 + r) * 128 + nf * 16 + c] = f2bf(p);
                }
        // O += P V  (P rows are wave-private; VT staged above)
        for (int kstep = 0; kstep < 4; ++kstep) {
            bf16x8 pf[2], vf[4];
            for (int mf = 0; mf < 2; ++mf)
                pf[mf] = *(const bf16x8*)&Pw[(mf * 16 + c) * 128 + kstep * 32 + quad * 8];
            for (int df = 0; df < 4; ++df)
                vf[df] = *(const bf16x8*)&lds[8192 + (df * 16 + c) * 128 + kstep * 32 + quad * 8];
            for (int mf = 0; mf < 2; ++mf)
                for (int df = 0; df < 4; ++df)
                    acc_o[mf][df] = __builtin_amdgcn_mfma_f32_16x16x32_bf16(pf[mf], vf[df],
                                                                            acc_o[mf][df], 0, 0, 0);
        }
        __syncthreads();
    }

    // reduce l over the 16 column-lanes of each quad
    for (int mf = 0; mf < 2; ++mf)
        for (int r = 0; r < 4; ++r) {
            float v = lsum[mf][r];
            v += __shfl_xor(v, 1);
            v += __shfl_xor(v, 2);
            v += __shfl_xor(v, 4);
            v += __shfl_xor(v, 8);
            lsum[mf][r] = v;
        }
    for (int mf = 0; mf < 2; ++mf)
        for (int r = 0; r < 4; ++r) {
            float inv = 1.0f / lsum[mf][r];
            int row_local = w * 32 + mf * 16 + quad * 4 + r;
            int n = qt * 128 + row_local;
            if (c == 0)
                rowscale[hb * N_ + n] = inv * (1.0f / 32768.0f);  // 1/(l*H*N)
            for (int df = 0; df < 4; ++df) {
                int col = h * 64 + df * 16 + c;
                ctx[((size_t)(b * N_ + n)) * D_ + col] = f2bf(acc_o[mf][df][r] * inv);
            }
        }
}

// ---------------- attn_mean: recompute S weighted by rowscale, column sums ----------------
// grid (kb=16, hb=32), 256 threads
__global__ __launch_bounds__(256) void k_amean(const unsigned short* __restrict__ Q,
                                               const unsigned short* __restrict__ Kc,
                                               const float* __restrict__ rowscale,
                                               float* __restrict__ amean) {
    __shared__ __attribute__((aligned(16))) unsigned short Klds[8192];
    __shared__ __attribute__((aligned(16))) unsigned short Qlds[8192];
    __shared__ float rs[128];
    __shared__ float colbuf[4 * 128];
    int t = threadIdx.x, lane = t & 63, w = t >> 6;
    int quad = lane >> 4, c = lane & 15;
    int kb = blockIdx.x, hb = blockIdx.y;
    int b = hb & 1;
    const unsigned short* kbase = Kc + (size_t)hb * (N_ * DK) + (size_t)kb * 8192;
    const unsigned short* qbase = Q + (size_t)hb * (N_ * DK);

    for (int i = 0; i < 4; ++i) {
        int ch = i * 256 + t;
        *(uint4*)&Klds[ch * 8] = *(const uint4*)&kbase[ch * 8];
    }
    float colacc[8] = {0.f, 0.f, 0.f, 0.f, 0.f, 0.f, 0.f, 0.f};
    for (int qt = 0; qt < 16; ++qt) {
        __syncthreads();
        for (int i = 0; i < 4; ++i) {
            int ch = i * 256 + t;
            *(uint4*)&Qlds[ch * 8] = *(const uint4*)&qbase[(size_t)qt * 8192 + ch * 8];
        }
        if (t < 128) rs[t] = rowscale[hb * N_ + qt * 128 + t];
        __syncthreads();
        f32x4 s[2][8];
        for (int mf = 0; mf < 2; ++mf)
            for (int nf = 0; nf < 8; ++nf)
                s[mf][nf] = (f32x4){0.f, 0.f, 0.f, 0.f};
        for (int ks = 0; ks < 2; ++ks) {
            bf16x8 qf2[2];
            for (int mf = 0; mf < 2; ++mf)
                qf2[mf] = *(const bf16x8*)&Qlds[(w * 32 + mf * 16 + c) * 64 + ks * 32 + quad * 8];
            for (int nf = 0; nf < 8; ++nf) {
                bf16x8 kf = *(const bf16x8*)&Klds[(nf * 16 + c) * 64 + ks * 32 + quad * 8];
                for (int mf = 0; mf < 2; ++mf)
                    s[mf][nf] = __builtin_amdgcn_mfma_f32_16x16x32_bf16(qf2[mf], kf,
                                                                        s[mf][nf], 0, 0, 0);
            }
        }
        for (int mf = 0; mf < 2; ++mf)
            for (int r = 0; r < 4; ++r) {
                float rscale = rs[w * 32 + mf * 16 + quad * 4 + r];
                for (int nf = 0; nf < 8; ++nf)
                    colacc[nf] += __expf(s[mf][nf][r] * 0.125f) * rscale;
            }
    }
    for (int nf = 0; nf < 8; ++nf) {
        float v = colacc[nf];
        v += __shfl_xor(v, 16);
        v += __shfl_xor(v, 32);
        if (quad == 0) colbuf[w * 128 + nf * 16 + c] = v;
    }
    __syncthreads();
    if (t < 128) {
        float sum = colbuf[t] + colbuf[128 + t] + colbuf[256 + t] + colbuf[384 + t];
        atomicAdd(&amean[b * N_ + kb * 128 + t], sum);
    }
}

extern "C" void kernel_launch(void* const* d_in, const int* in_sizes, int n_in,
                              void* d_out, int out_size, void* d_ws, size_t ws_size,
                              hipStream_t stream) {
    const float* x = (const float*)d_in[0];
    const float* w_qkv = (const float*)d_in[1];
    const float* b_qkv = (const float*)d_in[2];
    const float* w_out = (const float*)d_in[3];
    const float* b_out = (const float*)d_in[4];
    float* out = (float*)d_out;
    float* amean = out + 4194304;

    unsigned short* ws = (unsigned short*)d_ws;
    unsigned short* x_bf = ws;                   // 4 Mi elems (8 MB)
    unsigned short* wqkvT = x_bf + 4194304;      // 3 Mi (6 MB)
    unsigned short* woutT = wqkvT + 3145728;     // 1 Mi (2 MB)
    unsigned short* q_bf = woutT + 1048576;      // 4 Mi; k,v contiguous after
    unsigned short* k_bf = q_bf + 4194304;
    unsigned short* v_bf = k_bf + 4194304;
    unsigned short* vT_bf = v_bf + 4194304;      // 4 Mi
    unsigned short* ctx_bf = vT_bf + 4194304;    // 4 Mi
    float* rowscale = (float*)(ctx_bf + 4194304);  // 64 Ki floats

    hipMemsetAsync(amean, 0, 4096 * sizeof(float), stream);
    k_convert_x<<<2048, 256, 0, stream>>>(x, x_bf, 1048576);
    k_transpose_w<<<dim3(96, 32), dim3(32, 8), 0, stream>>>(w_qkv, wqkvT, 1024, 3072);
    k_transpose_w<<<dim3(32, 32), dim3(32, 8), 0, stream>>>(w_out, woutT, 1024, 1024);
    k_gemm<0><<<dim3(24, 32), 256, 0, stream>>>(x_bf, wqkvT, b_qkv, q_bf, 4096, 3072, 1024);
    k_transpose_v<<<dim3(64, 2, 32), dim3(32, 8), 0, stream>>>(v_bf, vT_bf);
    k_attn<<<dim3(16, 32), 256, 0, stream>>>(q_bf, k_bf, vT_bf, ctx_bf, rowscale);
    k_amean<<<dim3(16, 32), 256, 0, stream>>>(q_bf, k_bf, rowscale, amean);
    k_gemm<1><<<dim3(8, 32), 256, 0, stream>>>(ctx_bf, woutT, b_out, out, 4096, 1024, 1024);
}

// Round 2
// 266.966 us; speedup vs baseline: 1.1897x; 1.1897x over previous
//
#include <hip/hip_runtime.h>
#include <stdint.h>

#define B_ 2
#define N_ 2048
#define D_ 1024
#define H_ 16
#define DK 64

typedef __bf16 bf16x8 __attribute__((ext_vector_type(8)));
typedef short s16x4 __attribute__((ext_vector_type(4)));
typedef float f32x4 __attribute__((ext_vector_type(4)));

#define EXP2SC 0.18033688011112042f  // 0.125 * log2(e)

__device__ __forceinline__ unsigned short f2bf(float f) {
    unsigned int u = __float_as_uint(f);
    u = (u + 0x7FFFu + ((u >> 16) & 1u)) >> 16;
    return (unsigned short)u;
}

// async global->LDS, 16B per lane; lds dest must be wave-uniform base + lane*16
__device__ __forceinline__ void glds16(const void* g, void* l) {
    __builtin_amdgcn_global_load_lds(
        (const __attribute__((address_space(1))) void*)g,
        (__attribute__((address_space(3))) void*)l, 16, 0, 0);
}

// ---------------- convert x (f32 -> bf16) ----------------
__global__ __launch_bounds__(256) void k_convert_x(const float* __restrict__ x,
                                                   unsigned short* __restrict__ xb, int n4) {
    int i = blockIdx.x * blockDim.x + threadIdx.x;
    int stride = gridDim.x * blockDim.x;
    const float4* x4 = (const float4*)x;
    ushort4* o4 = (ushort4*)xb;
    for (; i < n4; i += stride) {
        float4 v = x4[i];
        ushort4 o;
        o.x = f2bf(v.x); o.y = f2bf(v.y); o.z = f2bf(v.z); o.w = f2bf(v.w);
        o4[i] = o;
    }
}

// ---------------- transpose+convert weights: w (K x C) f32 -> wT (C x K) bf16 ----------------
__global__ __launch_bounds__(256) void k_transpose_w(const float* __restrict__ w,
                                                     unsigned short* __restrict__ wT,
                                                     int K, int C) {
    __shared__ float tile[32][33];
    int c0 = blockIdx.x * 32, k0 = blockIdx.y * 32;
    int tx = threadIdx.x, ty = threadIdx.y;  // 32 x 8
    for (int s = 0; s < 4; ++s)
        tile[ty + 8 * s][tx] = w[(size_t)(k0 + ty + 8 * s) * C + c0 + tx];
    __syncthreads();
    for (int s = 0; s < 4; ++s)
        wT[(size_t)(c0 + ty + 8 * s) * K + k0 + tx] = f2bf(tile[tx][ty + 8 * s]);
}

// ---------------- GEMM: C(M x Nn) = A(M x K) * BT(Nn x K)^T + bias ----------------
// MODE 0: scatter q,k -> [HB][N][64]; v -> transposed [HB][64][N]
// MODE 1: fp32 store C row-major
template <int MODE>
__global__ __launch_bounds__(256) void k_gemm(const unsigned short* __restrict__ A,
                                              const unsigned short* __restrict__ BT,
                                              const float* __restrict__ bias,
                                              void* __restrict__ Cout,
                                              int M, int Nn, int K) {
    __shared__ __attribute__((aligned(16))) unsigned short Alds[128 * 64];
    __shared__ __attribute__((aligned(16))) unsigned short Blds[128 * 64];
    int t = threadIdx.x;
    int lane = t & 63, w = t >> 6;
    int quad = lane >> 4, c = lane & 15;
    int wm = w >> 1, wn = w & 1;
    int bi = blockIdx.y, bj = blockIdx.x;
    const unsigned short* Abase = A + (size_t)(bi * 128) * K;
    const unsigned short* Bbase = BT + (size_t)(bj * 128) * K;

    f32x4 acc[4][4];
#pragma unroll
    for (int mf = 0; mf < 4; ++mf)
#pragma unroll
        for (int nf = 0; nf < 4; ++nf)
            acc[mf][nf] = (f32x4){0.f, 0.f, 0.f, 0.f};

    for (int k0 = 0; k0 < K; k0 += 64) {
        __syncthreads();
#pragma unroll
        for (int i = 0; i < 4; ++i) {
            int ch = i * 256 + t;  // 0..1023
            int row = ch >> 3, kc = ch & 7;
            glds16(&Abase[(size_t)row * K + k0 + kc * 8], (char*)Alds + ch * 16);
            glds16(&Bbase[(size_t)row * K + k0 + kc * 8], (char*)Blds + ch * 16);
        }
        __syncthreads();
#pragma unroll
        for (int ks = 0; ks < 2; ++ks) {
            bf16x8 af[4], bfr[4];
#pragma unroll
            for (int mf = 0; mf < 4; ++mf)
                af[mf] = *(const bf16x8*)&Alds[(wm * 64 + mf * 16 + c) * 64 + ks * 32 + quad * 8];
#pragma unroll
            for (int nf = 0; nf < 4; ++nf)
                bfr[nf] = *(const bf16x8*)&Blds[(wn * 64 + nf * 16 + c) * 64 + ks * 32 + quad * 8];
#pragma unroll
            for (int mf = 0; mf < 4; ++mf)
#pragma unroll
                for (int nf = 0; nf < 4; ++nf)
                    acc[mf][nf] = __builtin_amdgcn_mfma_f32_16x16x32_bf16(af[mf], bfr[nf],
                                                                          acc[mf][nf], 0, 0, 0);
        }
    }

#pragma unroll
    for (int mf = 0; mf < 4; ++mf)
#pragma unroll
        for (int nf = 0; nf < 4; ++nf) {
            int j = bj * 128 + wn * 64 + nf * 16 + c;
            float bv = bias[j];
#pragma unroll
            for (int r = 0; r < 4; ++r) {
                int i = bi * 128 + wm * 64 + mf * 16 + quad * 4 + r;
                float v = acc[mf][nf][r] + bv;
                if (MODE == 0) {
                    int h = j / 192, r2 = j % 192;
                    int which = r2 >> 6, d = r2 & 63;
                    int b = i >> 11, n = i & 2047;
                    size_t dst;
                    if (which < 2)
                        dst = (size_t)which * 4194304 + (((size_t)(h * 2 + b) * 2048 + n) * 64 + d);
                    else
                        dst = (size_t)2 * 4194304 + (((size_t)(h * 2 + b) * 64 + d) * 2048 + n);
                    ((unsigned short*)Cout)[dst] = f2bf(v);
                } else {
                    ((float*)Cout)[(size_t)i * Nn + j] = v;
                }
            }
        }
}

// ---------------- attention: S^T = K Q^T (16x16x32), exp in-register, PV via 16x16x16 ----
// grid (qt=16, hb=32), 256 threads (4 waves, 32 q each).
__global__ __launch_bounds__(256) void k_attn(const unsigned short* __restrict__ Q,
                                              const unsigned short* __restrict__ Kc,
                                              const unsigned short* __restrict__ VT,
                                              unsigned short* __restrict__ ctx,
                                              float* __restrict__ lrs_out) {
    // K chunk: 64 keys x 64 d (8192 B); Vt chunk: 64 d-rows x 72 (64 keys + 8 pad) (9216 B)
    __shared__ __attribute__((aligned(16))) unsigned short lds[4096 + 4608];
    unsigned short* Klds = lds;
    unsigned short* Vlds = lds + 4096;
    int t = threadIdx.x, lane = t & 63, w = t >> 6;
    int quad = lane >> 4, c = lane & 15;
    int qt = blockIdx.x, hb = blockIdx.y;
    int h = hb >> 1, b = hb & 1;
    const unsigned short* qbase = Q + (size_t)hb * 131072 + (size_t)(qt * 128 + w * 32) * 64;
    const unsigned short* kbase = Kc + (size_t)hb * 131072;
    const unsigned short* vtbase = VT + (size_t)hb * 131072;

    // Q fragments (B-operand: n=q=lane&15, k=d=quad*8+j) straight from global
    bf16x8 qf[2][2];
#pragma unroll
    for (int qs = 0; qs < 2; ++qs)
#pragma unroll
        for (int ks = 0; ks < 2; ++ks)
            qf[qs][ks] = *(const bf16x8*)&qbase[(qs * 16 + c) * 64 + ks * 32 + quad * 8];

    f32x4 acc[2][4];
#pragma unroll
    for (int qs = 0; qs < 2; ++qs)
#pragma unroll
        for (int ds = 0; ds < 4; ++ds)
            acc[qs][ds] = (f32x4){0.f, 0.f, 0.f, 0.f};
    float lsum[2] = {0.f, 0.f};

    for (int kb = 0; kb < 32; ++kb) {
        __syncthreads();
        // stage K chunk (contiguous) via global_load_lds
#pragma unroll
        for (int i = 0; i < 2; ++i) {
            int ch = i * 256 + t;
            glds16(&kbase[(size_t)kb * 4096 + ch * 8], (char*)Klds + ch * 16);
        }
        // stage Vt chunk manually (padded row stride 72 breaks glds contiguity)
        uint4 vv[2];
#pragma unroll
        for (int i = 0; i < 2; ++i) {
            int ch = i * 256 + t;
            int row = ch >> 3, kc = ch & 7;
            vv[i] = *(const uint4*)&vtbase[(size_t)row * 2048 + kb * 64 + kc * 8];
        }
#pragma unroll
        for (int i = 0; i < 2; ++i) {
            int ch = i * 256 + t;
            int row = ch >> 3, kc = ch & 7;
            *(uint4*)&Vlds[row * 72 + kc * 8] = vv[i];
        }
        __syncthreads();

        // S^T tiles: [key-sub 4][q-sub 2]; C row=key=quad*4+r, col=q=c
        f32x4 st[4][2];
#pragma unroll
        for (int ksub = 0; ksub < 4; ++ksub)
#pragma unroll
            for (int qs = 0; qs < 2; ++qs)
                st[ksub][qs] = (f32x4){0.f, 0.f, 0.f, 0.f};
#pragma unroll
        for (int ks = 0; ks < 2; ++ks)
#pragma unroll
            for (int ksub = 0; ksub < 4; ++ksub) {
                bf16x8 kf = *(const bf16x8*)&Klds[(ksub * 16 + c) * 64 + ks * 32 + quad * 8];
#pragma unroll
                for (int qs = 0; qs < 2; ++qs)
                    st[ksub][qs] = __builtin_amdgcn_mfma_f32_16x16x32_bf16(kf, qf[qs][ks],
                                                                           st[ksub][qs], 0, 0, 0);
            }
        // exp + pack into PV A-frags (layout matches 16x16x16 A exactly) + PV
#pragma unroll
        for (int ksub = 0; ksub < 4; ++ksub) {
            s16x4 pf[2];
#pragma unroll
            for (int qs = 0; qs < 2; ++qs) {
                float p0 = __builtin_amdgcn_exp2f(st[ksub][qs][0] * EXP2SC);
                float p1 = __builtin_amdgcn_exp2f(st[ksub][qs][1] * EXP2SC);
                float p2 = __builtin_amdgcn_exp2f(st[ksub][qs][2] * EXP2SC);
                float p3 = __builtin_amdgcn_exp2f(st[ksub][qs][3] * EXP2SC);
                lsum[qs] += (p0 + p1) + (p2 + p3);
                pf[qs] = (s16x4){(short)f2bf(p0), (short)f2bf(p1),
                                 (short)f2bf(p2), (short)f2bf(p3)};
            }
            s16x4 vf[4];
#pragma unroll
            for (int ds = 0; ds < 4; ++ds)
                vf[ds] = *(const s16x4*)&Vlds[(ds * 16 + c) * 72 + ksub * 16 + quad * 4];
#pragma unroll
            for (int qs = 0; qs < 2; ++qs)
#pragma unroll
                for (int ds = 0; ds < 4; ++ds)
                    acc[qs][ds] = __builtin_amdgcn_mfma_f32_16x16x16bf16_1k(pf[qs], vf[ds],
                                                                            acc[qs][ds], 0, 0, 0);
        }
    }

    // l = sum over quads (q lives on lane&15)
    float linv[2];
#pragma unroll
    for (int qs = 0; qs < 2; ++qs) {
        float v = lsum[qs];
        v += __shfl_xor(v, 16);
        v += __shfl_xor(v, 32);
        if (lane < 16)
            lrs_out[hb * 2048 + qt * 128 + w * 32 + qs * 16 + c] =
                -(__builtin_amdgcn_logf(v) + 15.0f);  // log2(1/(l*H*N))
        linv[qs] = 1.0f / v;
    }
#pragma unroll
    for (int qs = 0; qs < 2; ++qs) {
        float ir[4];
#pragma unroll
        for (int r = 0; r < 4; ++r) ir[r] = __shfl(linv[qs], quad * 4 + r);
#pragma unroll
        for (int ds = 0; ds < 4; ++ds)
#pragma unroll
            for (int r = 0; r < 4; ++r) {
                int n = qt * 128 + w * 32 + qs * 16 + quad * 4 + r;
                ctx[((size_t)(b * 2048 + n)) * 1024 + h * 64 + ds * 16 + c] =
                    f2bf(acc[qs][ds][r] * ir[r]);
            }
    }
}

// ---------------- attn_mean: recompute S^T, weight via exp2(s*c + log2(rs)) ----------------
// grid (kt=16, hb=32), 256 threads; each wave owns 32 keys, K-frags in registers.
__global__ __launch_bounds__(256) void k_amean(const unsigned short* __restrict__ Q,
                                               const unsigned short* __restrict__ Kc,
                                               const float* __restrict__ lrs,
                                               float* __restrict__ amean) {
    __shared__ __attribute__((aligned(16))) unsigned short Qlds[128 * 64];
    __shared__ float rslds[128];
    int t = threadIdx.x, lane = t & 63, w = t >> 6;
    int quad = lane >> 4, c = lane & 15;
    int kt = blockIdx.x, hb = blockIdx.y, b = hb & 1;
    const unsigned short* kbase = Kc + (size_t)hb * 131072 + (size_t)(kt * 128 + w * 32) * 64;
    const unsigned short* qbase = Q + (size_t)hb * 131072;

    bf16x8 kf[2][2];
#pragma unroll
    for (int ksub = 0; ksub < 2; ++ksub)
#pragma unroll
        for (int ks = 0; ks < 2; ++ks)
            kf[ksub][ks] = *(const bf16x8*)&kbase[(ksub * 16 + c) * 64 + ks * 32 + quad * 8];

    f32x4 colacc[2];
    colacc[0] = (f32x4){0.f, 0.f, 0.f, 0.f};
    colacc[1] = (f32x4){0.f, 0.f, 0.f, 0.f};

    for (int qc = 0; qc < 16; ++qc) {
        __syncthreads();
#pragma unroll
        for (int i = 0; i < 4; ++i) {
            int ch = i * 256 + t;
            glds16(&qbase[(size_t)qc * 8192 + ch * 8], (char*)Qlds + ch * 16);
        }
        if (t < 128) rslds[t] = lrs[hb * 2048 + qc * 128 + t];
        __syncthreads();
#pragma unroll
        for (int qs = 0; qs < 8; ++qs) {
            f32x4 st[2];
            st[0] = (f32x4){0.f, 0.f, 0.f, 0.f};
            st[1] = (f32x4){0.f, 0.f, 0.f, 0.f};
#pragma unroll
            for (int ks = 0; ks < 2; ++ks) {
                bf16x8 qfr = *(const bf16x8*)&Qlds[(qs * 16 + c) * 64 + ks * 32 + quad * 8];
#pragma unroll
                for (int ksub = 0; ksub < 2; ++ksub)
                    st[ksub] = __builtin_amdgcn_mfma_f32_16x16x32_bf16(kf[ksub][ks], qfr,
                                                                       st[ksub], 0, 0, 0);
            }
            float rv = rslds[qs * 16 + c];
#pragma unroll
            for (int ksub = 0; ksub < 2; ++ksub)
#pragma unroll
                for (int r = 0; r < 4; ++r)
                    colacc[ksub][r] += __builtin_amdgcn_exp2f(st[ksub][r] * EXP2SC + rv);
        }
    }
    // reduce over q-lanes (c bits), then one atomic per key
#pragma unroll
    for (int ksub = 0; ksub < 2; ++ksub)
#pragma unroll
        for (int r = 0; r < 4; ++r) {
            float v = colacc[ksub][r];
            v += __shfl_xor(v, 1);
            v += __shfl_xor(v, 2);
            v += __shfl_xor(v, 4);
            v += __shfl_xor(v, 8);
            if (c == 0)
                atomicAdd(&amean[b * 2048 + kt * 128 + w * 32 + ksub * 16 + quad * 4 + r], v);
        }
}

extern "C" void kernel_launch(void* const* d_in, const int* in_sizes, int n_in,
                              void* d_out, int out_size, void* d_ws, size_t ws_size,
                              hipStream_t stream) {
    const float* x = (const float*)d_in[0];
    const float* w_qkv = (const float*)d_in[1];
    const float* b_qkv = (const float*)d_in[2];
    const float* w_out = (const float*)d_in[3];
    const float* b_out = (const float*)d_in[4];
    float* out = (float*)d_out;
    float* amean = out + 4194304;

    unsigned short* ws = (unsigned short*)d_ws;
    unsigned short* x_bf = ws;                   // 4 Mi elems
    unsigned short* wqkvT = x_bf + 4194304;      // 3 Mi
    unsigned short* woutT = wqkvT + 3145728;     // 1 Mi
    unsigned short* q_bf = woutT + 1048576;      // 4 Mi  [HB][N][64]
    unsigned short* k_bf = q_bf + 4194304;       // 4 Mi  [HB][N][64]
    unsigned short* vT_bf = k_bf + 4194304;      // 4 Mi  [HB][64][N] (written by gemm<0>)
    unsigned short* ctx_bf = vT_bf + 4194304;    // 4 Mi
    float* lrs = (float*)(ctx_bf + 4194304);     // 64 Ki floats

    hipMemsetAsync(amean, 0, 4096 * sizeof(float), stream);
    k_convert_x<<<2048, 256, 0, stream>>>(x, x_bf, 1048576);
    k_transpose_w<<<dim3(96, 32), dim3(32, 8), 0, stream>>>(w_qkv, wqkvT, 1024, 3072);
    k_transpose_w<<<dim3(32, 32), dim3(32, 8), 0, stream>>>(w_out, woutT, 1024, 1024);
    k_gemm<0><<<dim3(24, 32), 256, 0, stream>>>(x_bf, wqkvT, b_qkv, q_bf, 4096, 3072, 1024);
    k_attn<<<dim3(16, 32), 256, 0, stream>>>(q_bf, k_bf, vT_bf, ctx_bf, lrs);
    k_amean<<<dim3(16, 32), 256, 0, stream>>>(q_bf, k_bf, lrs, amean);
    k_gemm<1><<<dim3(8, 32), 256, 0, stream>>>(ctx_bf, woutT, b_out, out, 4096, 1024, 1024);
}

// Round 3
// 246.177 us; speedup vs baseline: 1.2902x; 1.0844x over previous
//
#include <hip/hip_runtime.h>
#include <hip/hip_bf16.h>
#include <stdint.h>

#define B_ 2
#define N_ 2048
#define D_ 1024
#define H_ 16
#define DK 64

typedef __bf16 bf16x8 __attribute__((ext_vector_type(8)));
typedef short s16x4 __attribute__((ext_vector_type(4)));
typedef float f32x4 __attribute__((ext_vector_type(4)));

#define EXP2SC 0.18033688011112042f  // 0.125 * log2(e)

__device__ __forceinline__ unsigned short f2bf(float f) {
    unsigned int u = __float_as_uint(f);
    u = (u + 0x7FFFu + ((u >> 16) & 1u)) >> 16;
    return (unsigned short)u;
}

__device__ __forceinline__ short2 pkbf(float a, float b) {
    __hip_bfloat162 t = __float22bfloat162_rn(float2{a, b});
    return *(short2*)&t;
}

// async global->LDS, 16B per lane; lds dest must be wave-uniform base + lane*16
__device__ __forceinline__ void glds16(const void* g, void* l) {
    __builtin_amdgcn_global_load_lds(
        (const __attribute__((address_space(1))) void*)g,
        (__attribute__((address_space(3))) void*)l, 16, 0, 0);
}

// ---------------- convert x (f32 -> bf16) ----------------
__global__ __launch_bounds__(256) void k_convert_x(const float* __restrict__ x,
                                                   unsigned short* __restrict__ xb, int n4) {
    int i = blockIdx.x * blockDim.x + threadIdx.x;
    int stride = gridDim.x * blockDim.x;
    const float4* x4 = (const float4*)x;
    ushort4* o4 = (ushort4*)xb;
    for (; i < n4; i += stride) {
        float4 v = x4[i];
        ushort4 o;
        o.x = f2bf(v.x); o.y = f2bf(v.y); o.z = f2bf(v.z); o.w = f2bf(v.w);
        o4[i] = o;
    }
}

// ---------------- transpose+convert weights: w (K x C) f32 -> wT (C x K) bf16 ----------------
__global__ __launch_bounds__(256) void k_transpose_w(const float* __restrict__ w,
                                                     unsigned short* __restrict__ wT,
                                                     int K, int C) {
    __shared__ float tile[32][33];
    int c0 = blockIdx.x * 32, k0 = blockIdx.y * 32;
    int tx = threadIdx.x, ty = threadIdx.y;  // 32 x 8
    for (int s = 0; s < 4; ++s)
        tile[ty + 8 * s][tx] = w[(size_t)(k0 + ty + 8 * s) * C + c0 + tx];
    __syncthreads();
    for (int s = 0; s < 4; ++s)
        wT[(size_t)(c0 + ty + 8 * s) * K + k0 + tx] = f2bf(tile[tx][ty + 8 * s]);
}

// ---------------- QKV GEMM: 128x128 tile; scatter q,k -> [HB][N][64]; v -> [HB][64][N] ----
__global__ __launch_bounds__(256) void k_gemm_qkv(const unsigned short* __restrict__ A,
                                                  const unsigned short* __restrict__ BT,
                                                  const float* __restrict__ bias,
                                                  unsigned short* __restrict__ Cout,
                                                  int M, int Nn, int K) {
    __shared__ __attribute__((aligned(16))) unsigned short Alds[128 * 64];
    __shared__ __attribute__((aligned(16))) unsigned short Blds[128 * 64];
    int t = threadIdx.x;
    int lane = t & 63, w = t >> 6;
    int quad = lane >> 4, c = lane & 15;
    int wm = w >> 1, wn = w & 1;
    int bi = blockIdx.y, bj = blockIdx.x;
    const unsigned short* Abase = A + (size_t)(bi * 128) * K;
    const unsigned short* Bbase = BT + (size_t)(bj * 128) * K;

    f32x4 acc[4][4];
#pragma unroll
    for (int mf = 0; mf < 4; ++mf)
#pragma unroll
        for (int nf = 0; nf < 4; ++nf)
            acc[mf][nf] = (f32x4){0.f, 0.f, 0.f, 0.f};

    for (int k0 = 0; k0 < K; k0 += 64) {
        __syncthreads();
#pragma unroll
        for (int i = 0; i < 4; ++i) {
            int ch = i * 256 + t;  // 0..1023
            int row = ch >> 3, kc = ch & 7;
            glds16(&Abase[(size_t)row * K + k0 + kc * 8], (char*)Alds + ch * 16);
            glds16(&Bbase[(size_t)row * K + k0 + kc * 8], (char*)Blds + ch * 16);
        }
        __syncthreads();
#pragma unroll
        for (int ks = 0; ks < 2; ++ks) {
            bf16x8 af[4], bfr[4];
#pragma unroll
            for (int mf = 0; mf < 4; ++mf)
                af[mf] = *(const bf16x8*)&Alds[(wm * 64 + mf * 16 + c) * 64 + ks * 32 + quad * 8];
#pragma unroll
            for (int nf = 0; nf < 4; ++nf)
                bfr[nf] = *(const bf16x8*)&Blds[(wn * 64 + nf * 16 + c) * 64 + ks * 32 + quad * 8];
#pragma unroll
            for (int mf = 0; mf < 4; ++mf)
#pragma unroll
                for (int nf = 0; nf < 4; ++nf)
                    acc[mf][nf] = __builtin_amdgcn_mfma_f32_16x16x32_bf16(af[mf], bfr[nf],
                                                                          acc[mf][nf], 0, 0, 0);
        }
    }

#pragma unroll
    for (int mf = 0; mf < 4; ++mf)
#pragma unroll
        for (int nf = 0; nf < 4; ++nf) {
            int j = bj * 128 + wn * 64 + nf * 16 + c;
            float bv = bias[j];
#pragma unroll
            for (int r = 0; r < 4; ++r) {
                int i = bi * 128 + wm * 64 + mf * 16 + quad * 4 + r;
                float v = acc[mf][nf][r] + bv;
                int h = j / 192, r2 = j % 192;
                int which = r2 >> 6, d = r2 & 63;
                int b = i >> 11, n = i & 2047;
                size_t dst;
                if (which < 2)
                    dst = (size_t)which * 4194304 + (((size_t)(h * 2 + b) * 2048 + n) * 64 + d);
                else
                    dst = (size_t)2 * 4194304 + (((size_t)(h * 2 + b) * 64 + d) * 2048 + n);
                Cout[dst] = f2bf(v);
            }
        }
}

// ---------------- out-proj GEMM: 64x128 tile, fp32 out ----------------
__global__ __launch_bounds__(256) void k_gemm_out(const unsigned short* __restrict__ A,
                                                  const unsigned short* __restrict__ BT,
                                                  const float* __restrict__ bias,
                                                  float* __restrict__ C,
                                                  int M, int Nn, int K) {
    __shared__ __attribute__((aligned(16))) unsigned short Alds[64 * 64];
    __shared__ __attribute__((aligned(16))) unsigned short Blds[128 * 64];
    int t = threadIdx.x;
    int lane = t & 63, w = t >> 6;
    int quad = lane >> 4, c = lane & 15;
    int wm = w >> 1, wn = w & 1;
    int bi = blockIdx.y, bj = blockIdx.x;
    const unsigned short* Abase = A + (size_t)(bi * 64) * K;
    const unsigned short* Bbase = BT + (size_t)(bj * 128) * K;

    f32x4 acc[2][4];
#pragma unroll
    for (int mf = 0; mf < 2; ++mf)
#pragma unroll
        for (int nf = 0; nf < 4; ++nf)
            acc[mf][nf] = (f32x4){0.f, 0.f, 0.f, 0.f};

    for (int k0 = 0; k0 < K; k0 += 64) {
        __syncthreads();
#pragma unroll
        for (int i = 0; i < 2; ++i) {
            int ch = i * 256 + t;  // 0..511
            int row = ch >> 3, kc = ch & 7;
            glds16(&Abase[(size_t)row * K + k0 + kc * 8], (char*)Alds + ch * 16);
        }
#pragma unroll
        for (int i = 0; i < 4; ++i) {
            int ch = i * 256 + t;  // 0..1023
            int row = ch >> 3, kc = ch & 7;
            glds16(&Bbase[(size_t)row * K + k0 + kc * 8], (char*)Blds + ch * 16);
        }
        __syncthreads();
#pragma unroll
        for (int ks = 0; ks < 2; ++ks) {
            bf16x8 af[2], bfr[4];
#pragma unroll
            for (int mf = 0; mf < 2; ++mf)
                af[mf] = *(const bf16x8*)&Alds[(wm * 32 + mf * 16 + c) * 64 + ks * 32 + quad * 8];
#pragma unroll
            for (int nf = 0; nf < 4; ++nf)
                bfr[nf] = *(const bf16x8*)&Blds[(wn * 64 + nf * 16 + c) * 64 + ks * 32 + quad * 8];
#pragma unroll
            for (int mf = 0; mf < 2; ++mf)
#pragma unroll
                for (int nf = 0; nf < 4; ++nf)
                    acc[mf][nf] = __builtin_amdgcn_mfma_f32_16x16x32_bf16(af[mf], bfr[nf],
                                                                          acc[mf][nf], 0, 0, 0);
        }
    }

#pragma unroll
    for (int mf = 0; mf < 2; ++mf)
#pragma unroll
        for (int nf = 0; nf < 4; ++nf) {
            int j = bj * 128 + wn * 64 + nf * 16 + c;
            float bv = bias[j];
#pragma unroll
            for (int r = 0; r < 4; ++r) {
                int i = bi * 64 + wm * 32 + mf * 16 + quad * 4 + r;
                C[(size_t)i * Nn + j] = acc[mf][nf][r] + bv;
            }
        }
}

// ---------------- attention: 512 threads, 8 waves x 16 q-rows; swizzled LDS ----------------
// grid (qt=16, hb=32). q/k: [HB][N][64] bf16, vT: [HB][64][N] bf16
__global__ __launch_bounds__(512) void k_attn(const unsigned short* __restrict__ Q,
                                              const unsigned short* __restrict__ Kc,
                                              const unsigned short* __restrict__ VT,
                                              unsigned short* __restrict__ ctx,
                                              float* __restrict__ lrs_out) {
    __shared__ __attribute__((aligned(16))) unsigned short lds[8192];  // K 8KB + V 8KB
    unsigned short* Klds = lds;
    unsigned short* Vlds = lds + 4096;
    int t = threadIdx.x, lane = t & 63, w = t >> 6;
    int quad = lane >> 4, c = lane & 15;
    int qt = blockIdx.x, hb = blockIdx.y;
    int h = hb >> 1, b = hb & 1;
    const unsigned short* qbase = Q + (size_t)hb * 131072 + (size_t)(qt * 128 + w * 16) * 64;
    const unsigned short* kbase = Kc + (size_t)hb * 131072;
    const unsigned short* vtbase = VT + (size_t)hb * 131072;

    // staging coords (same every chunk): LDS slot t -> logical (row, Bs), global block Bs^(row&7)
    int srow = t >> 3, sB = t & 7;
    int sgoff = srow * 64 + ((sB ^ (srow & 7)) * 8);   // elems within a 64x64 K chunk
    int vgoff = srow * 2048 + ((sB ^ (srow & 7)) * 8); // elems within VT (row stride N)

    // Q fragments (B-operand: n=q=c, k=d=quad*8+j), straight from global
    bf16x8 qf[2];
#pragma unroll
    for (int ks = 0; ks < 2; ++ks)
        qf[ks] = *(const bf16x8*)&qbase[c * 64 + ks * 32 + quad * 8];

    f32x4 acc[4];
#pragma unroll
    for (int ds = 0; ds < 4; ++ds) acc[ds] = (f32x4){0.f, 0.f, 0.f, 0.f};
    float lsum = 0.f;

    for (int kb = 0; kb < 32; ++kb) {
        __syncthreads();
        glds16(&kbase[(size_t)kb * 4096 + sgoff], (char*)Klds + t * 16);
        glds16(&vtbase[(size_t)kb * 64 + vgoff], (char*)Vlds + t * 16);
        __syncthreads();

        // S^T tiles: row=key=quad*4+r, col=q=c
        f32x4 st[4];
#pragma unroll
        for (int ksub = 0; ksub < 4; ++ksub) st[ksub] = (f32x4){0.f, 0.f, 0.f, 0.f};
#pragma unroll
        for (int ks = 0; ks < 2; ++ks)
#pragma unroll
            for (int ksub = 0; ksub < 4; ++ksub) {
                bf16x8 kf = *(const bf16x8*)&Klds[(ksub * 16 + c) * 64 +
                                                  (((ks * 4 + quad) ^ (c & 7)) * 8)];
                st[ksub] = __builtin_amdgcn_mfma_f32_16x16x32_bf16(kf, qf[ks], st[ksub], 0, 0, 0);
            }
        // exp in-register -> PV A-frags -> PV
#pragma unroll
        for (int ksub = 0; ksub < 4; ++ksub) {
            float p0 = __builtin_amdgcn_exp2f(st[ksub][0] * EXP2SC);
            float p1 = __builtin_amdgcn_exp2f(st[ksub][1] * EXP2SC);
            float p2 = __builtin_amdgcn_exp2f(st[ksub][2] * EXP2SC);
            float p3 = __builtin_amdgcn_exp2f(st[ksub][3] * EXP2SC);
            lsum += (p0 + p1) + (p2 + p3);
            short2 lo = pkbf(p0, p1), hi = pkbf(p2, p3);
            s16x4 pf = (s16x4){lo.x, lo.y, hi.x, hi.y};
            s16x4 vf[4];
#pragma unroll
            for (int ds = 0; ds < 4; ++ds) {
                int row = ds * 16 + c;
                vf[ds] = *(const s16x4*)&Vlds[row * 64 +
                                              (((2 * ksub + (quad >> 1)) ^ (row & 7)) * 8) +
                                              (quad & 1) * 4];
            }
#pragma unroll
            for (int ds = 0; ds < 4; ++ds)
                acc[ds] = __builtin_amdgcn_mfma_f32_16x16x16bf16_1k(pf, vf[ds], acc[ds], 0, 0, 0);
        }
    }

    // l: reduce over quads (q lives on c)
    float v = lsum;
    v += __shfl_xor(v, 16);
    v += __shfl_xor(v, 32);
    if (lane < 16)
        lrs_out[hb * 2048 + qt * 128 + w * 16 + c] =
            -(__builtin_amdgcn_logf(v) + 15.0f);  // log2(1/(l*H*N))
    float linv = 1.0f / v;
    float ir[4];
#pragma unroll
    for (int r = 0; r < 4; ++r) ir[r] = __shfl(linv, quad * 4 + r);
#pragma unroll
    for (int ds = 0; ds < 4; ++ds)
#pragma unroll
        for (int r = 0; r < 4; ++r) {
            int n = qt * 128 + w * 16 + quad * 4 + r;
            ctx[((size_t)(b * 2048 + n)) * 1024 + h * 64 + ds * 16 + c] =
                f2bf(acc[ds][r] * ir[r]);
        }
}

// ---------------- attn_mean: 512 threads, 8 waves x 16 keys; swizzled Q staging ----------
// grid (kt=16, hb=32)
__global__ __launch_bounds__(512) void k_amean(const unsigned short* __restrict__ Q,
                                               const unsigned short* __restrict__ Kc,
                                               const float* __restrict__ lrs,
                                               float* __restrict__ amean) {
    __shared__ __attribute__((aligned(16))) unsigned short Qlds[128 * 64];
    __shared__ float rslds[128];
    int t = threadIdx.x, lane = t & 63, w = t >> 6;
    int quad = lane >> 4, c = lane & 15;
    int kt = blockIdx.x, hb = blockIdx.y, b = hb & 1;
    const unsigned short* kbase = Kc + (size_t)hb * 131072 + (size_t)(kt * 128 + w * 16) * 64;
    const unsigned short* qbase = Q + (size_t)hb * 131072;

    // K A-frags in registers (m=key=c, k=d)
    bf16x8 kf[2];
#pragma unroll
    for (int ks = 0; ks < 2; ++ks)
        kf[ks] = *(const bf16x8*)&kbase[c * 64 + ks * 32 + quad * 8];

    f32x4 colacc = (f32x4){0.f, 0.f, 0.f, 0.f};

    for (int qc = 0; qc < 16; ++qc) {
        __syncthreads();
#pragma unroll
        for (int i = 0; i < 2; ++i) {
            int ch = i * 512 + t;  // 0..1023
            int row = ch >> 3, Bs = ch & 7;
            glds16(&qbase[(size_t)qc * 8192 + row * 64 + ((Bs ^ (row & 7)) * 8)],
                   (char*)Qlds + ch * 16);
        }
        if (t < 128) rslds[t] = lrs[hb * 2048 + qc * 128 + t];
        __syncthreads();
#pragma unroll
        for (int qs = 0; qs < 8; ++qs) {
            f32x4 st = (f32x4){0.f, 0.f, 0.f, 0.f};
#pragma unroll
            for (int ks = 0; ks < 2; ++ks) {
                bf16x8 qfr = *(const bf16x8*)&Qlds[(qs * 16 + c) * 64 +
                                                   (((ks * 4 + quad) ^ (c & 7)) * 8)];
                st = __builtin_amdgcn_mfma_f32_16x16x32_bf16(kf[ks], qfr, st, 0, 0, 0);
            }
            float rv = rslds[qs * 16 + c];
#pragma unroll
            for (int r = 0; r < 4; ++r)
                colacc[r] += __builtin_amdgcn_exp2f(st[r] * EXP2SC + rv);
        }
    }
    // reduce over q-lanes (c bits), then one atomic per key
#pragma unroll
    for (int r = 0; r < 4; ++r) {
        float v = colacc[r];
        v += __shfl_xor(v, 1);
        v += __shfl_xor(v, 2);
        v += __shfl_xor(v, 4);
        v += __shfl_xor(v, 8);
        if (c == 0)
            atomicAdd(&amean[b * 2048 + kt * 128 + w * 16 + quad * 4 + r], v);
    }
}

extern "C" void kernel_launch(void* const* d_in, const int* in_sizes, int n_in,
                              void* d_out, int out_size, void* d_ws, size_t ws_size,
                              hipStream_t stream) {
    const float* x = (const float*)d_in[0];
    const float* w_qkv = (const float*)d_in[1];
    const float* b_qkv = (const float*)d_in[2];
    const float* w_out = (const float*)d_in[3];
    const float* b_out = (const float*)d_in[4];
    float* out = (float*)d_out;
    float* amean = out + 4194304;

    unsigned short* ws = (unsigned short*)d_ws;
    unsigned short* x_bf = ws;                   // 4 Mi elems
    unsigned short* wqkvT = x_bf + 4194304;      // 3 Mi
    unsigned short* woutT = wqkvT + 3145728;     // 1 Mi
    unsigned short* q_bf = woutT + 1048576;      // 4 Mi  [HB][N][64]
    unsigned short* k_bf = q_bf + 4194304;       // 4 Mi  [HB][N][64]
    unsigned short* vT_bf = k_bf + 4194304;      // 4 Mi  [HB][64][N]
    unsigned short* ctx_bf = vT_bf + 4194304;    // 4 Mi
    float* lrs = (float*)(ctx_bf + 4194304);     // 64 Ki floats

    hipMemsetAsync(amean, 0, 4096 * sizeof(float), stream);
    k_convert_x<<<2048, 256, 0, stream>>>(x, x_bf, 1048576);
    k_transpose_w<<<dim3(96, 32), dim3(32, 8), 0, stream>>>(w_qkv, wqkvT, 1024, 3072);
    k_transpose_w<<<dim3(32, 32), dim3(32, 8), 0, stream>>>(w_out, woutT, 1024, 1024);
    k_gemm_qkv<<<dim3(24, 32), 256, 0, stream>>>(x_bf, wqkvT, b_qkv, q_bf, 4096, 3072, 1024);
    k_attn<<<dim3(16, 32), 512, 0, stream>>>(q_bf, k_bf, vT_bf, ctx_bf, lrs);
    k_amean<<<dim3(16, 32), 512, 0, stream>>>(q_bf, k_bf, lrs, amean);
    k_gemm_out<<<dim3(8, 64), 256, 0, stream>>>(ctx_bf, woutT, b_out, out, 4096, 1024, 1024);
}

// Round 4
// 222.667 us; speedup vs baseline: 1.4264x; 1.1056x over previous
//
#include <hip/hip_runtime.h>
#include <hip/hip_bf16.h>
#include <stdint.h>

#define B_ 2
#define N_ 2048
#define D_ 1024
#define H_ 16
#define DK 64

typedef __bf16 bf16x8 __attribute__((ext_vector_type(8)));
typedef short s16x4 __attribute__((ext_vector_type(4)));
typedef float f32x4 __attribute__((ext_vector_type(4)));

#define EXP2SC 0.18033688011112042f  // 0.125 * log2(e)

__device__ __forceinline__ unsigned short f2bf(float f) {
    unsigned int u = __float_as_uint(f);
    u = (u + 0x7FFFu + ((u >> 16) & 1u)) >> 16;
    return (unsigned short)u;
}

__device__ __forceinline__ short2 pkbf(float a, float b) {
    __hip_bfloat162 t = __float22bfloat162_rn(float2{a, b});
    return *(short2*)&t;
}

// async global->LDS, 16B per lane; lds dest must be wave-uniform base + lane*16
__device__ __forceinline__ void glds16(const void* g, void* l) {
    __builtin_amdgcn_global_load_lds(
        (const __attribute__((address_space(1))) void*)g,
        (__attribute__((address_space(3))) void*)l, 16, 0, 0);
}

// ---------------- convert x (f32 -> bf16) ----------------
__global__ __launch_bounds__(256) void k_convert_x(const float* __restrict__ x,
                                                   unsigned short* __restrict__ xb, int n4) {
    int i = blockIdx.x * blockDim.x + threadIdx.x;
    int stride = gridDim.x * blockDim.x;
    const float4* x4 = (const float4*)x;
    ushort4* o4 = (ushort4*)xb;
    for (; i < n4; i += stride) {
        float4 v = x4[i];
        ushort4 o;
        o.x = f2bf(v.x); o.y = f2bf(v.y); o.z = f2bf(v.z); o.w = f2bf(v.w);
        o4[i] = o;
    }
}

// ---------------- transpose+convert weights: w (K x C) f32 -> wT (C x K) bf16 ----------------
__global__ __launch_bounds__(256) void k_transpose_w(const float* __restrict__ w,
                                                     unsigned short* __restrict__ wT,
                                                     int K, int C) {
    __shared__ float tile[32][33];
    int c0 = blockIdx.x * 32, k0 = blockIdx.y * 32;
    int tx = threadIdx.x, ty = threadIdx.y;  // 32 x 8
    for (int s = 0; s < 4; ++s)
        tile[ty + 8 * s][tx] = w[(size_t)(k0 + ty + 8 * s) * C + c0 + tx];
    __syncthreads();
    for (int s = 0; s < 4; ++s)
        wT[(size_t)(c0 + ty + 8 * s) * K + k0 + tx] = f2bf(tile[tx][ty + 8 * s]);
}

// ---------------- QKV GEMM: 128x128 tile; swizzled LDS; scatter q,k,vT ----------------
__global__ __launch_bounds__(256) void k_gemm_qkv(const unsigned short* __restrict__ A,
                                                  const unsigned short* __restrict__ BT,
                                                  const float* __restrict__ bias,
                                                  unsigned short* __restrict__ Cout,
                                                  int M, int Nn, int K) {
    __shared__ __attribute__((aligned(16))) unsigned short Alds[128 * 64];
    __shared__ __attribute__((aligned(16))) unsigned short Blds[128 * 64];
    int t = threadIdx.x;
    int lane = t & 63, w = t >> 6;
    int quad = lane >> 4, c = lane & 15;
    int wm = w >> 1, wn = w & 1;
    int bi = blockIdx.y, bj = blockIdx.x;
    const unsigned short* Abase = A + (size_t)(bi * 128) * K;
    const unsigned short* Bbase = BT + (size_t)(bj * 128) * K;

    f32x4 acc[4][4];
#pragma unroll
    for (int mf = 0; mf < 4; ++mf)
#pragma unroll
        for (int nf = 0; nf < 4; ++nf)
            acc[mf][nf] = (f32x4){0.f, 0.f, 0.f, 0.f};

    // swizzled staging: LDS slot ch holds global block ((ch&7) ^ (row&7)) of row
    for (int k0 = 0; k0 < K; k0 += 64) {
        __syncthreads();
#pragma unroll
        for (int i = 0; i < 4; ++i) {
            int ch = i * 256 + t;  // 0..1023
            int row = ch >> 3, kc = (ch & 7) ^ (row & 7);
            glds16(&Abase[(size_t)row * K + k0 + kc * 8], (char*)Alds + ch * 16);
            glds16(&Bbase[(size_t)row * K + k0 + kc * 8], (char*)Blds + ch * 16);
        }
        __syncthreads();
#pragma unroll
        for (int ks = 0; ks < 2; ++ks) {
            bf16x8 af[4], bfr[4];
#pragma unroll
            for (int mf = 0; mf < 4; ++mf)
                af[mf] = *(const bf16x8*)&Alds[(wm * 64 + mf * 16 + c) * 64 +
                                               (((ks * 4 + quad) ^ (c & 7)) * 8)];
#pragma unroll
            for (int nf = 0; nf < 4; ++nf)
                bfr[nf] = *(const bf16x8*)&Blds[(wn * 64 + nf * 16 + c) * 64 +
                                                (((ks * 4 + quad) ^ (c & 7)) * 8)];
#pragma unroll
            for (int mf = 0; mf < 4; ++mf)
#pragma unroll
                for (int nf = 0; nf < 4; ++nf)
                    acc[mf][nf] = __builtin_amdgcn_mfma_f32_16x16x32_bf16(af[mf], bfr[nf],
                                                                          acc[mf][nf], 0, 0, 0);
        }
    }

#pragma unroll
    for (int mf = 0; mf < 4; ++mf)
#pragma unroll
        for (int nf = 0; nf < 4; ++nf) {
            int j = bj * 128 + wn * 64 + nf * 16 + c;
            float bv = bias[j];
            int h = j / 192, r2 = j % 192;
            int which = r2 >> 6, d = r2 & 63;
#pragma unroll
            for (int r = 0; r < 4; ++r) {
                int i = bi * 128 + wm * 64 + mf * 16 + quad * 4 + r;
                float v = acc[mf][nf][r] + bv;
                int b = i >> 11, n = i & 2047;
                size_t dst;
                if (which < 2)
                    dst = (size_t)which * 4194304 + (((size_t)(h * 2 + b) * 2048 + n) * 64 + d);
                else
                    dst = (size_t)2 * 4194304 + (((size_t)(h * 2 + b) * 64 + d) * 2048 + n);
                Cout[dst] = f2bf(v);
            }
        }
}

// ---------------- out-proj GEMM: 64x128 tile, swizzled LDS, fp32 out ----------------
__global__ __launch_bounds__(256) void k_gemm_out(const unsigned short* __restrict__ A,
                                                  const unsigned short* __restrict__ BT,
                                                  const float* __restrict__ bias,
                                                  float* __restrict__ C,
                                                  int M, int Nn, int K) {
    __shared__ __attribute__((aligned(16))) unsigned short Alds[64 * 64];
    __shared__ __attribute__((aligned(16))) unsigned short Blds[128 * 64];
    int t = threadIdx.x;
    int lane = t & 63, w = t >> 6;
    int quad = lane >> 4, c = lane & 15;
    int wm = w >> 1, wn = w & 1;
    int bi = blockIdx.y, bj = blockIdx.x;
    const unsigned short* Abase = A + (size_t)(bi * 64) * K;
    const unsigned short* Bbase = BT + (size_t)(bj * 128) * K;

    f32x4 acc[2][4];
#pragma unroll
    for (int mf = 0; mf < 2; ++mf)
#pragma unroll
        for (int nf = 0; nf < 4; ++nf)
            acc[mf][nf] = (f32x4){0.f, 0.f, 0.f, 0.f};

    for (int k0 = 0; k0 < K; k0 += 64) {
        __syncthreads();
#pragma unroll
        for (int i = 0; i < 2; ++i) {
            int ch = i * 256 + t;  // 0..511
            int row = ch >> 3, kc = (ch & 7) ^ (row & 7);
            glds16(&Abase[(size_t)row * K + k0 + kc * 8], (char*)Alds + ch * 16);
        }
#pragma unroll
        for (int i = 0; i < 4; ++i) {
            int ch = i * 256 + t;  // 0..1023
            int row = ch >> 3, kc = (ch & 7) ^ (row & 7);
            glds16(&Bbase[(size_t)row * K + k0 + kc * 8], (char*)Blds + ch * 16);
        }
        __syncthreads();
#pragma unroll
        for (int ks = 0; ks < 2; ++ks) {
            bf16x8 af[2], bfr[4];
#pragma unroll
            for (int mf = 0; mf < 2; ++mf)
                af[mf] = *(const bf16x8*)&Alds[(wm * 32 + mf * 16 + c) * 64 +
                                               (((ks * 4 + quad) ^ (c & 7)) * 8)];
#pragma unroll
            for (int nf = 0; nf < 4; ++nf)
                bfr[nf] = *(const bf16x8*)&Blds[(wn * 64 + nf * 16 + c) * 64 +
                                                (((ks * 4 + quad) ^ (c & 7)) * 8)];
#pragma unroll
            for (int mf = 0; mf < 2; ++mf)
#pragma unroll
                for (int nf = 0; nf < 4; ++nf)
                    acc[mf][nf] = __builtin_amdgcn_mfma_f32_16x16x32_bf16(af[mf], bfr[nf],
                                                                          acc[mf][nf], 0, 0, 0);
        }
    }

#pragma unroll
    for (int mf = 0; mf < 2; ++mf)
#pragma unroll
        for (int nf = 0; nf < 4; ++nf) {
            int j = bj * 128 + wn * 64 + nf * 16 + c;
            float bv = bias[j];
#pragma unroll
            for (int r = 0; r < 4; ++r) {
                int i = bi * 64 + wm * 32 + mf * 16 + quad * 4 + r;
                C[(size_t)i * Nn + j] = acc[mf][nf][r] + bv;
            }
        }
}

// ---------------- attention: 512 threads, 8 waves x 16 q-rows; swizzled LDS ----------------
// grid (qt=16, hb=32). q/k: [HB][N][64] bf16, vT: [HB][64][N] bf16
__global__ __launch_bounds__(512) void k_attn(const unsigned short* __restrict__ Q,
                                              const unsigned short* __restrict__ Kc,
                                              const unsigned short* __restrict__ VT,
                                              unsigned short* __restrict__ ctx,
                                              float* __restrict__ lrs_out) {
    __shared__ __attribute__((aligned(16))) unsigned short lds[8192];  // K 8KB + V 8KB
    unsigned short* Klds = lds;
    unsigned short* Vlds = lds + 4096;
    int t = threadIdx.x, lane = t & 63, w = t >> 6;
    int quad = lane >> 4, c = lane & 15;
    int qt = blockIdx.x, hb = blockIdx.y;
    int h = hb >> 1, b = hb & 1;
    const unsigned short* qbase = Q + (size_t)hb * 131072 + (size_t)(qt * 128 + w * 16) * 64;
    const unsigned short* kbase = Kc + (size_t)hb * 131072;
    const unsigned short* vtbase = VT + (size_t)hb * 131072;

    // staging coords (same every chunk): LDS slot t -> logical (row, Bs), global block Bs^(row&7)
    int srow = t >> 3, sB = t & 7;
    int sgoff = srow * 64 + ((sB ^ (srow & 7)) * 8);   // elems within a 64x64 K chunk
    int vgoff = srow * 2048 + ((sB ^ (srow & 7)) * 8); // elems within VT (row stride N)

    // Q fragments (B-operand: n=q=c, k=d=quad*8+j), straight from global
    bf16x8 qf[2];
#pragma unroll
    for (int ks = 0; ks < 2; ++ks)
        qf[ks] = *(const bf16x8*)&qbase[c * 64 + ks * 32 + quad * 8];

    f32x4 acc[4];
#pragma unroll
    for (int ds = 0; ds < 4; ++ds) acc[ds] = (f32x4){0.f, 0.f, 0.f, 0.f};
    float lsum = 0.f;

    for (int kb = 0; kb < 32; ++kb) {
        __syncthreads();
        glds16(&kbase[(size_t)kb * 4096 + sgoff], (char*)Klds + t * 16);
        glds16(&vtbase[(size_t)kb * 64 + vgoff], (char*)Vlds + t * 16);
        __syncthreads();

        // S^T tiles: row=key=quad*4+r, col=q=c
        f32x4 st[4];
#pragma unroll
        for (int ksub = 0; ksub < 4; ++ksub) st[ksub] = (f32x4){0.f, 0.f, 0.f, 0.f};
#pragma unroll
        for (int ks = 0; ks < 2; ++ks)
#pragma unroll
            for (int ksub = 0; ksub < 4; ++ksub) {
                bf16x8 kf = *(const bf16x8*)&Klds[(ksub * 16 + c) * 64 +
                                                  (((ks * 4 + quad) ^ (c & 7)) * 8)];
                st[ksub] = __builtin_amdgcn_mfma_f32_16x16x32_bf16(kf, qf[ks], st[ksub], 0, 0, 0);
            }
        // exp in-register -> PV A-frags -> PV
#pragma unroll
        for (int ksub = 0; ksub < 4; ++ksub) {
            float p0 = __builtin_amdgcn_exp2f(st[ksub][0] * EXP2SC);
            float p1 = __builtin_amdgcn_exp2f(st[ksub][1] * EXP2SC);
            float p2 = __builtin_amdgcn_exp2f(st[ksub][2] * EXP2SC);
            float p3 = __builtin_amdgcn_exp2f(st[ksub][3] * EXP2SC);
            lsum += (p0 + p1) + (p2 + p3);
            short2 lo = pkbf(p0, p1), hi = pkbf(p2, p3);
            s16x4 pf = (s16x4){lo.x, lo.y, hi.x, hi.y};
            s16x4 vf[4];
#pragma unroll
            for (int ds = 0; ds < 4; ++ds) {
                int row = ds * 16 + c;
                vf[ds] = *(const s16x4*)&Vlds[row * 64 +
                                              (((2 * ksub + (quad >> 1)) ^ (row & 7)) * 8) +
                                              (quad & 1) * 4];
            }
#pragma unroll
            for (int ds = 0; ds < 4; ++ds)
                acc[ds] = __builtin_amdgcn_mfma_f32_16x16x16bf16_1k(pf, vf[ds], acc[ds], 0, 0, 0);
        }
    }

    // l: reduce over quads (q lives on c)
    float v = lsum;
    v += __shfl_xor(v, 16);
    v += __shfl_xor(v, 32);
    if (lane < 16)
        lrs_out[hb * 2048 + qt * 128 + w * 16 + c] =
            -(__builtin_amdgcn_logf(v) + 15.0f);  // log2(1/(l*H*N))
    float linv = 1.0f / v;
    float ir[4];
#pragma unroll
    for (int r = 0; r < 4; ++r) ir[r] = __shfl(linv, quad * 4 + r);
#pragma unroll
    for (int ds = 0; ds < 4; ++ds)
#pragma unroll
        for (int r = 0; r < 4; ++r) {
            int n = qt * 128 + w * 16 + quad * 4 + r;
            ctx[((size_t)(b * 2048 + n)) * 1024 + h * 64 + ds * 16 + c] =
                f2bf(acc[ds][r] * ir[r]);
        }
}

// ---------------- attn_mean: 512 threads, 8 waves x 16 keys; swizzled Q staging ----------
// grid (kt=16, hb=32)
__global__ __launch_bounds__(512) void k_amean(const unsigned short* __restrict__ Q,
                                               const unsigned short* __restrict__ Kc,
                                               const float* __restrict__ lrs,
                                               float* __restrict__ amean) {
    __shared__ __attribute__((aligned(16))) unsigned short Qlds[128 * 64];
    __shared__ float rslds[128];
    int t = threadIdx.x, lane = t & 63, w = t >> 6;
    int quad = lane >> 4, c = lane & 15;
    int kt = blockIdx.x, hb = blockIdx.y, b = hb & 1;
    const unsigned short* kbase = Kc + (size_t)hb * 131072 + (size_t)(kt * 128 + w * 16) * 64;
    const unsigned short* qbase = Q + (size_t)hb * 131072;

    // K A-frags in registers (m=key=c, k=d)
    bf16x8 kf[2];
#pragma unroll
    for (int ks = 0; ks < 2; ++ks)
        kf[ks] = *(const bf16x8*)&kbase[c * 64 + ks * 32 + quad * 8];

    f32x4 colacc = (f32x4){0.f, 0.f, 0.f, 0.f};

    for (int qc = 0; qc < 16; ++qc) {
        __syncthreads();
#pragma unroll
        for (int i = 0; i < 2; ++i) {
            int ch = i * 512 + t;  // 0..1023
            int row = ch >> 3, Bs = ch & 7;
            glds16(&qbase[(size_t)qc * 8192 + row * 64 + ((Bs ^ (row & 7)) * 8)],
                   (char*)Qlds + ch * 16);
        }
        if (t < 128) rslds[t] = lrs[hb * 2048 + qc * 128 + t];
        __syncthreads();
#pragma unroll
        for (int qs = 0; qs < 8; ++qs) {
            f32x4 st = (f32x4){0.f, 0.f, 0.f, 0.f};
#pragma unroll
            for (int ks = 0; ks < 2; ++ks) {
                bf16x8 qfr = *(const bf16x8*)&Qlds[(qs * 16 + c) * 64 +
                                                   (((ks * 4 + quad) ^ (c & 7)) * 8)];
                st = __builtin_amdgcn_mfma_f32_16x16x32_bf16(kf[ks], qfr, st, 0, 0, 0);
            }
            float rv = rslds[qs * 16 + c];
#pragma unroll
            for (int r = 0; r < 4; ++r)
                colacc[r] += __builtin_amdgcn_exp2f(st[r] * EXP2SC + rv);
        }
    }
    // reduce over q-lanes (c bits), then one atomic per key
#pragma unroll
    for (int r = 0; r < 4; ++r) {
        float v = colacc[r];
        v += __shfl_xor(v, 1);
        v += __shfl_xor(v, 2);
        v += __shfl_xor(v, 4);
        v += __shfl_xor(v, 8);
        if (c == 0)
            atomicAdd(&amean[b * 2048 + kt * 128 + w * 16 + quad * 4 + r], v);
    }
}

extern "C" void kernel_launch(void* const* d_in, const int* in_sizes, int n_in,
                              void* d_out, int out_size, void* d_ws, size_t ws_size,
                              hipStream_t stream) {
    const float* x = (const float*)d_in[0];
    const float* w_qkv = (const float*)d_in[1];
    const float* b_qkv = (const float*)d_in[2];
    const float* w_out = (const float*)d_in[3];
    const float* b_out = (const float*)d_in[4];
    float* out = (float*)d_out;
    float* amean = out + 4194304;

    unsigned short* ws = (unsigned short*)d_ws;
    unsigned short* x_bf = ws;                   // 4 Mi elems
    unsigned short* wqkvT = x_bf + 4194304;      // 3 Mi
    unsigned short* woutT = wqkvT + 3145728;     // 1 Mi
    unsigned short* q_bf = woutT + 1048576;      // 4 Mi  [HB][N][64]
    unsigned short* k_bf = q_bf + 4194304;       // 4 Mi  [HB][N][64]
    unsigned short* vT_bf = k_bf + 4194304;      // 4 Mi  [HB][64][N]
    unsigned short* ctx_bf = vT_bf + 4194304;    // 4 Mi
    float* lrs = (float*)(ctx_bf + 4194304);     // 64 Ki floats

    hipMemsetAsync(amean, 0, 4096 * sizeof(float), stream);
    k_convert_x<<<2048, 256, 0, stream>>>(x, x_bf, 1048576);
    k_transpose_w<<<dim3(96, 32), dim3(32, 8), 0, stream>>>(w_qkv, wqkvT, 1024, 3072);
    k_transpose_w<<<dim3(32, 32), dim3(32, 8), 0, stream>>>(w_out, woutT, 1024, 1024);
    k_gemm_qkv<<<dim3(24, 32), 256, 0, stream>>>(x_bf, wqkvT, b_qkv, q_bf, 4096, 3072, 1024);
    k_attn<<<dim3(16, 32), 512, 0, stream>>>(q_bf, k_bf, vT_bf, ctx_bf, lrs);
    k_amean<<<dim3(16, 32), 512, 0, stream>>>(q_bf, k_bf, lrs, amean);
    k_gemm_out<<<dim3(8, 64), 256, 0, stream>>>(ctx_bf, woutT, b_out, out, 4096, 1024, 1024);
}